// Round 3
// baseline (1400.670 us; speedup 1.0000x reference)
//
#include <hip/hip_runtime.h>
#include <hip/hip_bf16.h>

#define BATCH 16
#define HH 128
#define WW 128
#define NPIX (BATCH*HH*WW)   // 262144
#define KCH 256
#define DCH 128
#define TAPS 81

// ---------------- zero counts ----------------
__global__ __launch_bounds__(256) void k_zero(int* __restrict__ counts) {
    counts[threadIdx.x] = 0;
}

// ---------------- conv 9x9 (1->256) + gate + per-pixel argmax + histogram ----------------
// Fast f32 4-acc FMA scan with top-2 tracking. Near-ties (gap < 1e-4) are re-resolved
// with the EXACT arithmetic a numpy mirror would use: serial t=0..80, separate
// mul-then-add rounding (no FMA), f32 accumulator — bit-identical to numpy
// shift-and-accumulate / einsum(optimize=False) conv on any IEEE machine.
__global__ __launch_bounds__(256) void k_conv_argmax(
    const float* __restrict__ x, const float* __restrict__ wconv,
    const float* __restrict__ gate,
    int* __restrict__ idxb, float* __restrict__ valb, int* __restrict__ counts)
{
    __shared__ float sig[KCH];
    __shared__ int hist[KCH];
    int tid = threadIdx.x;
    sig[tid] = 1.0f / (1.0f + expf(-gate[tid]));   // blockDim == 256 == KCH
    hist[tid] = 0;
    __syncthreads();

    int p = blockIdx.x * 256 + tid;
    int b = p >> 14, rem = p & 16383, y = rem >> 7, xc = rem & 127;
    const float* xb = x + ((size_t)b << 14);

    // stage 9x9 input patch (zero-padded) into registers
    float px[TAPS];
#pragma unroll
    for (int i = 0; i < 9; i++) {
        int yy = y + i - 4;
#pragma unroll
        for (int j = 0; j < 9; j++) {
            int xx = xc + j - 4;
            px[i*9+j] = (yy >= 0 && yy < HH && xx >= 0 && xx < WW) ? xb[(yy<<7)+xx] : 0.0f;
        }
    }

    float best = -1.0f, best2 = -1.0f; int bi = 0;
    for (int k = 0; k < KCH; k++) {
        const float* wk = wconv + k * TAPS;   // wave-uniform -> scalar loads
        float a0 = 0.f, a1 = 0.f, a2 = 0.f, a3 = 0.f;
#pragma unroll
        for (int t = 0; t < 80; t += 4) {
            a0 = fmaf(px[t+0], wk[t+0], a0);
            a1 = fmaf(px[t+1], wk[t+1], a1);
            a2 = fmaf(px[t+2], wk[t+2], a2);
            a3 = fmaf(px[t+3], wk[t+3], a3);
        }
        a0 = fmaf(px[80], wk[80], a0);
        float z = (a0 + a1) + (a2 + a3);
        float a = fmaxf(z, 0.0f) * sig[k];
        if (a > best) { best2 = best; best = a; bi = k; }     // strict > : first-index argmax
        else if (a > best2) { best2 = a; }
    }

    // near-tie: redo all channels in exact numpy-mirror f32 order (serial mul+add, no FMA)
    if (best - best2 < 1e-4f) {
        float bestn = -1.0f; int bin = 0;
        for (int k = 0; k < KCH; k++) {
            const float* wk = wconv + k * TAPS;
            float acc = 0.0f;
            for (int t = 0; t < TAPS; t++)
                acc = __fadd_rn(acc, __fmul_rn(px[t], wk[t]));
            float a = fmaxf(acc, 0.0f) * sig[k];
            if (a > bestn) { bestn = a; bin = k; }
        }
        bi = bin;
        best = bestn;
    }

    idxb[p] = bi;
    valb[p] = best;

    atomicAdd(&hist[bi], 1);
    __syncthreads();
    atomicAdd(&counts[tid], hist[tid]);
}

// ---------------- usage EMA (f64, exact +1e-6 denominator) ----------------
__global__ __launch_bounds__(256) void k_usage(
    const int* __restrict__ counts, const float* __restrict__ ema,
    float* __restrict__ out_usage)
{
    int k = threadIdx.x;
    double pfrac = (double)counts[k] / (262144.0 + 1e-6);
    out_usage[k] = (float)((double)ema[k] * 0.99 + pfrac * 0.01);
}

// ---------------- storage-type helpers (f32 sbuf preferred; bf16 fallback) ----------------
template<typename T> __device__ inline T to_store(float v);
template<> __device__ inline float to_store<float>(float v) { return v; }
template<> __device__ inline __hip_bfloat16 to_store<__hip_bfloat16>(float v) { return __float2bfloat16(v); }
template<typename T> __device__ inline float from_store(T v);
template<> __device__ inline float from_store<float>(float v) { return v; }
template<> __device__ inline float from_store<__hip_bfloat16>(__hip_bfloat16 v) { return __bfloat162float(v); }

// ---------------- fused: h = relu(val*w_down[:,k*]+b_down); a2 = relu(W_up h + b_up);
//                  s[t][p] = sum_k a2[k] * w_conv[k][80-t]  (conv-T inner contraction) ----------------
template<typename T>
__global__ __launch_bounds__(256) void k_proj(
    const int* __restrict__ idxb, const float* __restrict__ valb,
    const float* __restrict__ wdown, const float* __restrict__ bdown,
    const float* __restrict__ wup, const float* __restrict__ bup,
    const float* __restrict__ wconv,
    T* __restrict__ sbuf)
{
    int p = blockIdx.x * 256 + threadIdx.x;
    int kk = idxb[p];
    float v = valb[p];

    float h[DCH];
#pragma unroll
    for (int d = 0; d < DCH; d++)
        h[d] = fmaxf(fmaf(v, wdown[(d << 8) + kk], bdown[d]), 0.0f);

    float sacc[TAPS];
#pragma unroll
    for (int t = 0; t < TAPS; t++) sacc[t] = 0.0f;

    for (int k = 0; k < KCH; k++) {
        const float* wr = wup + (k << 7);     // wave-uniform -> scalar loads
        float a0 = bup[k], a1 = 0.f, a2 = 0.f, a3 = 0.f;
#pragma unroll
        for (int d = 0; d < DCH; d += 4) {
            a0 = fmaf(wr[d+0], h[d+0], a0);
            a1 = fmaf(wr[d+1], h[d+1], a1);
            a2 = fmaf(wr[d+2], h[d+2], a2);
            a3 = fmaf(wr[d+3], h[d+3], a3);
        }
        float a2v = fmaxf((a0 + a1) + (a2 + a3), 0.0f);
        const float* wc = wconv + k * TAPS;   // wave-uniform
#pragma unroll
        for (int t = 0; t < TAPS; t++)
            sacc[t] = fmaf(a2v, wc[80 - t], sacc[t]);   // flipped kernel
    }
#pragma unroll
    for (int t = 0; t < TAPS; t++)
        sbuf[(size_t)t * NPIX + p] = to_store<T>(sacc[t]);
}

// ---------------- gather shifted taps: x_hat[y,x] = sum_{i,j} s[(i,j)][y+i-4, x+j-4] ----------------
template<typename T>
__global__ __launch_bounds__(256) void k_gather(
    const T* __restrict__ sbuf, float* __restrict__ xhat)
{
    int p = blockIdx.x * 256 + threadIdx.x;
    int b = p >> 14, rem = p & 16383, y = rem >> 7, xc = rem & 127;
    float acc = 0.0f;
#pragma unroll
    for (int i = 0; i < 9; i++) {
        int yy = y + i - 4;
        if (yy < 0 || yy >= HH) continue;
#pragma unroll
        for (int j = 0; j < 9; j++) {
            int xx = xc + j - 4;
            if (xx < 0 || xx >= WW) continue;
            int t = i * 9 + j;
            acc += from_store<T>(sbuf[(size_t)t * NPIX + (b << 14) + (yy << 7) + xx]);
        }
    }
    xhat[p] = acc;
}

extern "C" void kernel_launch(void* const* d_in, const int* in_sizes, int n_in,
                              void* d_out, int out_size, void* d_ws, size_t ws_size,
                              hipStream_t stream)
{
    const float* x     = (const float*)d_in[0];
    const float* wconv = (const float*)d_in[1];
    const float* gate  = (const float*)d_in[2];
    const float* wdown = (const float*)d_in[3];
    const float* bdown = (const float*)d_in[4];
    const float* wup   = (const float*)d_in[5];
    const float* bup   = (const float*)d_in[6];
    const float* ema   = (const float*)d_in[7];
    float* out = (float*)d_out;

    char* ws = (char*)d_ws;
    int*   idxb   = (int*)ws;                                  // 1 MB
    float* valb   = (float*)(ws + (size_t)NPIX * 4);           // 1 MB
    int*   counts = (int*)(ws + (size_t)NPIX * 8);             // 1 KB
    char*  sstart = ws + (size_t)NPIX * 8 + 1024;

    size_t need_f32 = (size_t)NPIX * 8 + 1024 + (size_t)TAPS * NPIX * sizeof(float);

    k_zero<<<1, 256, 0, stream>>>(counts);
    k_conv_argmax<<<NPIX/256, 256, 0, stream>>>(x, wconv, gate, idxb, valb, counts);
    k_usage<<<1, 256, 0, stream>>>(counts, ema, out + NPIX);

    if (ws_size >= need_f32) {
        float* sbuf = (float*)sstart;
        k_proj<float><<<NPIX/256, 256, 0, stream>>>(idxb, valb, wdown, bdown, wup, bup, wconv, sbuf);
        k_gather<float><<<NPIX/256, 256, 0, stream>>>(sbuf, out);
    } else {
        __hip_bfloat16* sbuf = (__hip_bfloat16*)sstart;
        k_proj<__hip_bfloat16><<<NPIX/256, 256, 0, stream>>>(idxb, valb, wdown, bdown, wup, bup, wconv, sbuf);
        k_gather<__hip_bfloat16><<<NPIX/256, 256, 0, stream>>>(sbuf, out);
    }
}

// Round 4
// 358.104 us; speedup vs baseline: 3.9113x; 3.9113x over previous
//
#include <hip/hip_runtime.h>
#include <hip/hip_bf16.h>

#define BATCH 16
#define HH 128
#define WW 128
#define NPIX (BATCH*HH*WW)   // 262144
#define KCH 256
#define DCH 128
#define TAPS 81

// ---------------- prep: zero counts, compute zero-bias flag ----------------
__global__ __launch_bounds__(256) void k_prep(
    const float* __restrict__ bdown, const float* __restrict__ bup,
    int* __restrict__ counts, int* __restrict__ flag)
{
    __shared__ float red[256];
    int t = threadIdx.x;
    counts[t] = 0;
    float m = fabsf(bup[t]);
    if (t < DCH) m = fmaxf(m, fabsf(bdown[t]));
    red[t] = m;
    __syncthreads();
    for (int s = 128; s > 0; s >>= 1) {
        if (t < s) red[t] = fmaxf(red[t], red[t + s]);
        __syncthreads();
    }
    if (t == 0) flag[0] = (red[0] == 0.0f) ? 1 : 0;
}

// ---------------- conv 9x9 (1->256) + gate + per-pixel argmax + histogram ----------------
// Fast f32 4-acc FMA scan with top-2 tracking; near-ties re-resolved in exact
// numpy-mirror f32 order (serial mul+add, no FMA). [passed R3]
__global__ __launch_bounds__(256) void k_conv_argmax(
    const float* __restrict__ x, const float* __restrict__ wconv,
    const float* __restrict__ gate,
    int* __restrict__ idxb, float* __restrict__ valb, float2* __restrict__ vkout,
    int* __restrict__ counts)
{
    __shared__ float sig[KCH];
    __shared__ int hist[KCH];
    int tid = threadIdx.x;
    sig[tid] = 1.0f / (1.0f + expf(-gate[tid]));   // blockDim == 256 == KCH
    hist[tid] = 0;
    __syncthreads();

    int p = blockIdx.x * 256 + tid;
    int b = p >> 14, rem = p & 16383, y = rem >> 7, xc = rem & 127;
    const float* xb = x + ((size_t)b << 14);

    float px[TAPS];
#pragma unroll
    for (int i = 0; i < 9; i++) {
        int yy = y + i - 4;
#pragma unroll
        for (int j = 0; j < 9; j++) {
            int xx = xc + j - 4;
            px[i*9+j] = (yy >= 0 && yy < HH && xx >= 0 && xx < WW) ? xb[(yy<<7)+xx] : 0.0f;
        }
    }

    float best = -1.0f, best2 = -1.0f; int bi = 0;
    for (int k = 0; k < KCH; k++) {
        const float* wk = wconv + k * TAPS;   // wave-uniform -> scalar loads
        float a0 = 0.f, a1 = 0.f, a2 = 0.f, a3 = 0.f;
#pragma unroll
        for (int t = 0; t < 80; t += 4) {
            a0 = fmaf(px[t+0], wk[t+0], a0);
            a1 = fmaf(px[t+1], wk[t+1], a1);
            a2 = fmaf(px[t+2], wk[t+2], a2);
            a3 = fmaf(px[t+3], wk[t+3], a3);
        }
        a0 = fmaf(px[80], wk[80], a0);
        float z = (a0 + a1) + (a2 + a3);
        float a = fmaxf(z, 0.0f) * sig[k];
        if (a > best) { best2 = best; best = a; bi = k; }     // strict > : first-index argmax
        else if (a > best2) { best2 = a; }
    }

    if (best - best2 < 1e-4f) {   // near-tie: exact numpy-mirror f32 order
        float bestn = -1.0f; int bin = 0;
        for (int k = 0; k < KCH; k++) {
            const float* wk = wconv + k * TAPS;
            float acc = 0.0f;
            for (int t = 0; t < TAPS; t++)
                acc = __fadd_rn(acc, __fmul_rn(px[t], wk[t]));
            float a = fmaxf(acc, 0.0f) * sig[k];
            if (a > bestn) { bestn = a; bin = k; }
        }
        bi = bin;
        best = bestn;
    }

    idxb[p] = bi;
    valb[p] = best;
    vkout[p] = make_float2(best, __int_as_float(bi));

    atomicAdd(&hist[bi], 1);
    __syncthreads();
    atomicAdd(&counts[tid], hist[tid]);
}

// ---------------- usage EMA (f64, exact +1e-6 denominator) ----------------
__global__ __launch_bounds__(256) void k_usage(
    const int* __restrict__ counts, const float* __restrict__ ema,
    float* __restrict__ out_usage)
{
    int k = threadIdx.x;
    double pfrac = (double)counts[k] / (262144.0 + 1e-6);
    out_usage[k] = (float)((double)ema[k] * 0.99 + pfrac * 0.01);
}

// ---------------- tables: M = wup·relu(wdown); G[t][j] = sum_k relu(M[k,j])·wconv[k,80-t] ----------------
// One block per j (argmax channel). f64 accumulation -> negligible table error.
__global__ __launch_bounds__(256) void k_tables(
    const float* __restrict__ wdown, const float* __restrict__ wup,
    const float* __restrict__ wconv, float* __restrict__ G)
{
    int j = blockIdx.x;
    int k = threadIdx.x;
    __shared__ float wd[DCH];
    __shared__ float mrelu[KCH];
    if (k < DCH) wd[k] = fmaxf(wdown[(k << 8) + j], 0.0f);
    __syncthreads();
    const float* wr = wup + (k << 7);
    double acc = 0.0;
    for (int d = 0; d < DCH; d++) acc += (double)wr[d] * (double)wd[d];
    mrelu[k] = fmaxf((float)acc, 0.0f);
    __syncthreads();
    if (k < TAPS) {
        double g = 0.0;
        for (int kk = 0; kk < KCH; kk++)
            g += (double)mrelu[kk] * (double)wconv[kk * TAPS + 80 - k];
        G[(k << 8) + j] = (float)g;   // layout [t][j]
    }
}

// ---------------- fast reconstruction: x_hat[p] = sum_t v[n_t]·G[t, kk[n_t]] ----------------
__global__ __launch_bounds__(256) void k_recon(
    const int* __restrict__ flag, const float2* __restrict__ vk,
    const float* __restrict__ G, float* __restrict__ out)
{
    if (flag[0] == 0) return;
    __shared__ float2 tile[24][25];   // 16x16 tile + 4-halo, padded inner dim
    int lx = threadIdx.x & 15, ly = threadIdx.x >> 4;
    int x0 = blockIdx.x << 4, y0 = blockIdx.y << 4;
    int b = blockIdx.z;
    const float2* vkb = vk + ((size_t)b << 14);
    for (int i = threadIdx.x; i < 576; i += 256) {
        int r = i / 24, c = i - r * 24;
        int gy = y0 + r - 4, gx = x0 + c - 4;
        float2 e = make_float2(0.0f, 0.0f);
        if (gy >= 0 && gy < HH && gx >= 0 && gx < WW) e = vkb[(gy << 7) + gx];
        tile[r][c] = e;
    }
    __syncthreads();
    float acc = 0.0f;
#pragma unroll
    for (int i = 0; i < 9; i++)
#pragma unroll
        for (int jj = 0; jj < 9; jj++) {
            float2 e = tile[ly + i][lx + jj];
            int kn = __float_as_int(e.y);          // argmax channel of neighbor (0 in halo, v=0)
            acc = fmaf(e.x, G[((i * 9 + jj) << 8) + kn], acc);
        }
    out[((size_t)b << 14) + ((y0 + ly) << 7) + (x0 + lx)] = acc;
}

// ---------------- storage-type helpers (generic fallback path) ----------------
template<typename T> __device__ inline T to_store(float v);
template<> __device__ inline float to_store<float>(float v) { return v; }
template<> __device__ inline __hip_bfloat16 to_store<__hip_bfloat16>(float v) { return __float2bfloat16(v); }
template<typename T> __device__ inline float from_store(T v);
template<> __device__ inline float from_store<float>(float v) { return v; }
template<> __device__ inline float from_store<__hip_bfloat16>(__hip_bfloat16 v) { return __bfloat162float(v); }

// ---------------- GENERIC FALLBACK (nonzero biases): proven R3 path, flag-guarded ----------------
template<typename T>
__global__ __launch_bounds__(256) void k_proj_fb(
    const int* __restrict__ flag,
    const int* __restrict__ idxb, const float* __restrict__ valb,
    const float* __restrict__ wdown, const float* __restrict__ bdown,
    const float* __restrict__ wup, const float* __restrict__ bup,
    const float* __restrict__ wconv,
    T* __restrict__ sbuf)
{
    if (flag[0] != 0) return;
    int p = blockIdx.x * 256 + threadIdx.x;
    int kk = idxb[p];
    float v = valb[p];

    float h[DCH];
#pragma unroll
    for (int d = 0; d < DCH; d++)
        h[d] = fmaxf(fmaf(v, wdown[(d << 8) + kk], bdown[d]), 0.0f);

    float sacc[TAPS];
#pragma unroll
    for (int t = 0; t < TAPS; t++) sacc[t] = 0.0f;

    for (int k = 0; k < KCH; k++) {
        const float* wr = wup + (k << 7);
        float a0 = bup[k], a1 = 0.f, a2 = 0.f, a3 = 0.f;
#pragma unroll
        for (int d = 0; d < DCH; d += 4) {
            a0 = fmaf(wr[d+0], h[d+0], a0);
            a1 = fmaf(wr[d+1], h[d+1], a1);
            a2 = fmaf(wr[d+2], h[d+2], a2);
            a3 = fmaf(wr[d+3], h[d+3], a3);
        }
        float a2v = fmaxf((a0 + a1) + (a2 + a3), 0.0f);
        const float* wc = wconv + k * TAPS;
#pragma unroll
        for (int t = 0; t < TAPS; t++)
            sacc[t] = fmaf(a2v, wc[80 - t], sacc[t]);
    }
#pragma unroll
    for (int t = 0; t < TAPS; t++)
        sbuf[(size_t)t * NPIX + p] = to_store<T>(sacc[t]);
}

template<typename T>
__global__ __launch_bounds__(256) void k_gather_fb(
    const int* __restrict__ flag,
    const T* __restrict__ sbuf, float* __restrict__ xhat)
{
    if (flag[0] != 0) return;
    int p = blockIdx.x * 256 + threadIdx.x;
    int b = p >> 14, rem = p & 16383, y = rem >> 7, xc = rem & 127;
    float acc = 0.0f;
#pragma unroll
    for (int i = 0; i < 9; i++) {
        int yy = y + i - 4;
        if (yy < 0 || yy >= HH) continue;
#pragma unroll
        for (int j = 0; j < 9; j++) {
            int xx = xc + j - 4;
            if (xx < 0 || xx >= WW) continue;
            int t = i * 9 + j;
            acc += from_store<T>(sbuf[(size_t)t * NPIX + (b << 14) + (yy << 7) + xx]);
        }
    }
    xhat[p] = acc;
}

extern "C" void kernel_launch(void* const* d_in, const int* in_sizes, int n_in,
                              void* d_out, int out_size, void* d_ws, size_t ws_size,
                              hipStream_t stream)
{
    const float* x     = (const float*)d_in[0];
    const float* wconv = (const float*)d_in[1];
    const float* gate  = (const float*)d_in[2];
    const float* wdown = (const float*)d_in[3];
    const float* bdown = (const float*)d_in[4];
    const float* wup   = (const float*)d_in[5];
    const float* bup   = (const float*)d_in[6];
    const float* ema   = (const float*)d_in[7];
    float* out = (float*)d_out;

    char* ws = (char*)d_ws;
    int*    idxb   = (int*)ws;                                      // 1 MB
    float*  valb   = (float*)(ws + (size_t)NPIX * 4);               // 1 MB
    float2* vk     = (float2*)(ws + (size_t)NPIX * 8);              // 2 MB
    int*    counts = (int*)(ws + (size_t)NPIX * 16);                // 1 KB
    int*    flag   = (int*)(ws + (size_t)NPIX * 16 + 1024);         // 1 KB
    float*  G      = (float*)(ws + (size_t)NPIX * 16 + 2048);       // 84 KB
    char*   sstart = ws + (size_t)NPIX * 16 + 2048 + 86016;

    size_t need_f32 = ((size_t)NPIX * 16 + 2048 + 86016) + (size_t)TAPS * NPIX * sizeof(float);

    k_prep<<<1, 256, 0, stream>>>(bdown, bup, counts, flag);
    k_conv_argmax<<<NPIX/256, 256, 0, stream>>>(x, wconv, gate, idxb, valb, vk, counts);
    k_usage<<<1, 256, 0, stream>>>(counts, ema, out + NPIX);
    k_tables<<<KCH, 256, 0, stream>>>(wdown, wup, wconv, G);

    // fast path (zero biases — the benchmark's actual inputs)
    k_recon<<<dim3(8, 8, 16), 256, 0, stream>>>(flag, vk, G, out);

    // generic fallback (nonzero biases) — early-exits when flag==1
    if (ws_size >= need_f32) {
        float* sbuf = (float*)sstart;
        k_proj_fb<float><<<NPIX/256, 256, 0, stream>>>(flag, idxb, valb, wdown, bdown, wup, bup, wconv, sbuf);
        k_gather_fb<float><<<NPIX/256, 256, 0, stream>>>(flag, sbuf, out);
    } else {
        __hip_bfloat16* sbuf = (__hip_bfloat16*)sstart;
        k_proj_fb<__hip_bfloat16><<<NPIX/256, 256, 0, stream>>>(flag, idxb, valb, wdown, bdown, wup, bup, wconv, sbuf);
        k_gather_fb<__hip_bfloat16><<<NPIX/256, 256, 0, stream>>>(flag, sbuf, out);
    }
}